// Round 1
// baseline (1755.612 us; speedup 1.0000x reference)
//
#include <hip/hip_runtime.h>

#define D_MODEL 1024
#define N_HEADS 16
#define D_K     64
#define BB      2
#define SS      2048
#define M_TOT   (BB * SS)          // 4096

// ---------------------------------------------------------------------------
// Generic NT GEMM: C = scale * (A @ W^T) [+ bias], A:[M,K] rm, W:[N,K] rm.
// MODE 0: C[m*N + n] plain row-major.
// MODE 1: head-split store: b=m/S, s=m%S, h=n/64, d=n%64 ->
//         C[((b*H + h)*S + s)*64 + d]   (for q/k/v projections)
// blockIdx.z batches via strides (scores GEMM).
// Tile 64x64, K-step 16, 256 threads, 4x4 micro-tile per thread.
// ---------------------------------------------------------------------------
template <int MODE, bool HAS_BIAS>
__global__ __launch_bounds__(256) void gemm_nt(
    const float* __restrict__ A, const float* __restrict__ W,
    const float* __restrict__ bias, float* __restrict__ C,
    int M, int N, int K, long sA, long sW, long sC, float scale)
{
    const int z = blockIdx.z;
    A += (long)z * sA;
    W += (long)z * sW;
    C += (long)z * sC;

    const int n0 = blockIdx.x * 64;
    const int m0 = blockIdx.y * 64;
    const int t  = threadIdx.x;
    const int tx = t & 15;          // micro-tile col group
    const int ty = t >> 4;          // micro-tile row group

    __shared__ float As[16][68];    // [k][m], +4 pad keeps 16B alignment
    __shared__ float Bs[16][68];    // [k][n]

    const int lr = t >> 2;          // 0..63 : row (A) / col (W) being loaded
    const int lc = (t & 3) * 4;     // 0,4,8,12 : k offset

    float acc[4][4] = {};

    for (int k0 = 0; k0 < K; k0 += 16) {
        const float4 av = *(const float4*)&A[(long)(m0 + lr) * K + k0 + lc];
        const float4 wv = *(const float4*)&W[(long)(n0 + lr) * K + k0 + lc];
        __syncthreads();
        As[lc + 0][lr] = av.x; As[lc + 1][lr] = av.y;
        As[lc + 2][lr] = av.z; As[lc + 3][lr] = av.w;
        Bs[lc + 0][lr] = wv.x; Bs[lc + 1][lr] = wv.y;
        Bs[lc + 2][lr] = wv.z; Bs[lc + 3][lr] = wv.w;
        __syncthreads();
#pragma unroll
        for (int kk = 0; kk < 16; ++kk) {
            const float4 a = *(const float4*)&As[kk][ty * 4];
            const float4 b = *(const float4*)&Bs[kk][tx * 4];
            acc[0][0] += a.x * b.x; acc[0][1] += a.x * b.y;
            acc[0][2] += a.x * b.z; acc[0][3] += a.x * b.w;
            acc[1][0] += a.y * b.x; acc[1][1] += a.y * b.y;
            acc[1][2] += a.y * b.z; acc[1][3] += a.y * b.w;
            acc[2][0] += a.z * b.x; acc[2][1] += a.z * b.y;
            acc[2][2] += a.z * b.z; acc[2][3] += a.z * b.w;
            acc[3][0] += a.w * b.x; acc[3][1] += a.w * b.y;
            acc[3][2] += a.w * b.z; acc[3][3] += a.w * b.w;
        }
    }

    const int cols = n0 + tx * 4;
    float4 bv = make_float4(0.f, 0.f, 0.f, 0.f);
    if (HAS_BIAS) bv = *(const float4*)&bias[cols];

#pragma unroll
    for (int i = 0; i < 4; ++i) {
        const int m = m0 + ty * 4 + i;
        float4 r;
        r.x = acc[i][0] * scale + bv.x;
        r.y = acc[i][1] * scale + bv.y;
        r.z = acc[i][2] * scale + bv.z;
        r.w = acc[i][3] * scale + bv.w;
        if (MODE == 0) {
            *(float4*)&C[(long)m * N + cols] = r;
        } else {
            const int b = m >> 11;         // m / S (S=2048)
            const int s = m & 2047;
            const int h = cols >> 6;       // whole 64-col tile is one head
            const int d = cols & 63;
            *(float4*)&C[(((long)(b * N_HEADS + h) * SS) + s) * 64 + d] = r;
        }
    }
}

// ---------------------------------------------------------------------------
// Row softmax in-place: one block per row of 2048, 256 threads x 8 elems.
// ---------------------------------------------------------------------------
__global__ __launch_bounds__(256) void softmax_rows(float* __restrict__ attn)
{
    const long row = blockIdx.x;
    float* p = attn + row * (long)SS;
    const int t = threadIdx.x;

    float4 v0 = *(const float4*)&p[t * 4];
    float4 v1 = *(const float4*)&p[(t + 256) * 4];

    float m = fmaxf(fmaxf(fmaxf(v0.x, v0.y), fmaxf(v0.z, v0.w)),
                    fmaxf(fmaxf(v1.x, v1.y), fmaxf(v1.z, v1.w)));
#pragma unroll
    for (int off = 32; off >= 1; off >>= 1)
        m = fmaxf(m, __shfl_xor(m, off));

    __shared__ float red[8];
    if ((t & 63) == 0) red[t >> 6] = m;
    __syncthreads();
    m = fmaxf(fmaxf(red[0], red[1]), fmaxf(red[2], red[3]));

    v0.x = __expf(v0.x - m); v0.y = __expf(v0.y - m);
    v0.z = __expf(v0.z - m); v0.w = __expf(v0.w - m);
    v1.x = __expf(v1.x - m); v1.y = __expf(v1.y - m);
    v1.z = __expf(v1.z - m); v1.w = __expf(v1.w - m);

    float s = (v0.x + v0.y + v0.z + v0.w) + (v1.x + v1.y + v1.z + v1.w);
#pragma unroll
    for (int off = 32; off >= 1; off >>= 1)
        s += __shfl_xor(s, off);
    if ((t & 63) == 0) red[4 + (t >> 6)] = s;
    __syncthreads();
    s = (red[4] + red[5]) + (red[6] + red[7]);

    const float r = 1.0f / s;
    v0.x *= r; v0.y *= r; v0.z *= r; v0.w *= r;
    v1.x *= r; v1.y *= r; v1.z *= r; v1.w *= r;

    *(float4*)&p[t * 4] = v0;
    *(float4*)&p[(t + 256) * 4] = v1;
}

// ---------------------------------------------------------------------------
// PV: oh[b, s, h*64+d] = sum_j attn[b,h,s,j] * vh[b,h,j,d]   (NN GEMM)
// Per (b,h): M=2048, N=64, K=2048. Tile 64(M) x 64(N) x 16(K).
// ---------------------------------------------------------------------------
__global__ __launch_bounds__(256) void gemm_nn_pv(
    const float* __restrict__ attn, const float* __restrict__ vh,
    float* __restrict__ oh)
{
    const int z = blockIdx.z;          // b*H + h
    const int b = z >> 4;
    const int h = z & 15;
    const float* A  = attn + (long)z * SS * SS;  // [2048, 2048]
    const float* Bm = vh   + (long)z * SS * 64;  // [2048, 64]

    const int m0 = blockIdx.y * 64;
    const int t  = threadIdx.x;
    const int tx = t & 15;
    const int ty = t >> 4;

    __shared__ float As[16][68];
    __shared__ float Bs[16][68];

    const int lr = t >> 2;             // A: row
    const int lc = (t & 3) * 4;        // A: k offset
    const int bk = t >> 4;             // B: k row
    const int bn = (t & 15) * 4;       // B: col

    float acc[4][4] = {};

    for (int k0 = 0; k0 < SS; k0 += 16) {
        const float4 av = *(const float4*)&A[(long)(m0 + lr) * SS + k0 + lc];
        const float4 bvv = *(const float4*)&Bm[(long)(k0 + bk) * 64 + bn];
        __syncthreads();
        As[lc + 0][lr] = av.x; As[lc + 1][lr] = av.y;
        As[lc + 2][lr] = av.z; As[lc + 3][lr] = av.w;
        *(float4*)&Bs[bk][bn] = bvv;
        __syncthreads();
#pragma unroll
        for (int kk = 0; kk < 16; ++kk) {
            const float4 a = *(const float4*)&As[kk][ty * 4];
            const float4 bb = *(const float4*)&Bs[kk][tx * 4];
            acc[0][0] += a.x * bb.x; acc[0][1] += a.x * bb.y;
            acc[0][2] += a.x * bb.z; acc[0][3] += a.x * bb.w;
            acc[1][0] += a.y * bb.x; acc[1][1] += a.y * bb.y;
            acc[1][2] += a.y * bb.z; acc[1][3] += a.y * bb.w;
            acc[2][0] += a.z * bb.x; acc[2][1] += a.z * bb.y;
            acc[2][2] += a.z * bb.z; acc[2][3] += a.z * bb.w;
            acc[3][0] += a.w * bb.x; acc[3][1] += a.w * bb.y;
            acc[3][2] += a.w * bb.z; acc[3][3] += a.w * bb.w;
        }
    }

    const int d0 = tx * 4;
#pragma unroll
    for (int i = 0; i < 4; ++i) {
        const int m = m0 + ty * 4 + i;
        float4 r;
        r.x = acc[i][0]; r.y = acc[i][1]; r.z = acc[i][2]; r.w = acc[i][3];
        *(float4*)&oh[((long)(b * SS + m)) * D_MODEL + h * 64 + d0] = r;
    }
}

// ---------------------------------------------------------------------------
extern "C" void kernel_launch(void* const* d_in, const int* in_sizes, int n_in,
                              void* d_out, int out_size, void* d_ws, size_t ws_size,
                              hipStream_t stream)
{
    const float* q  = (const float*)d_in[0];
    const float* k  = (const float*)d_in[1];
    const float* v  = (const float*)d_in[2];
    const float* wq = (const float*)d_in[3];
    const float* bq = (const float*)d_in[4];
    const float* wk = (const float*)d_in[5];
    const float* bk = (const float*)d_in[6];
    const float* wv = (const float*)d_in[7];
    const float* bv = (const float*)d_in[8];
    const float* wo = (const float*)d_in[9];
    const float* bo = (const float*)d_in[10];

    float* out  = (float*)d_out;                         // [2,2048,1024]
    float* attn = out + (long)BB * SS * D_MODEL;         // [2,16,2048,2048]

    float* ws = (float*)d_ws;
    const long HSZ = (long)BB * N_HEADS * SS * D_K;      // 4,194,304
    float* qh = ws;                                      // [B,H,S,64]
    float* kh = qh + HSZ;
    float* vh = kh + HSZ;
    float* oh = vh + HSZ;                                // [B,S,D] merged

    const dim3 blk(256);

    // Projections: M=4096, N=1024, K=1024, head-split output
    const dim3 gproj(D_MODEL / 64, M_TOT / 64, 1);
    hipLaunchKernelGGL((gemm_nt<1, true>), gproj, blk, 0, stream,
                       q, wq, bq, qh, M_TOT, D_MODEL, D_MODEL, 0L, 0L, 0L, 1.0f);
    hipLaunchKernelGGL((gemm_nt<1, true>), gproj, blk, 0, stream,
                       k, wk, bk, kh, M_TOT, D_MODEL, D_MODEL, 0L, 0L, 0L, 1.0f);
    hipLaunchKernelGGL((gemm_nt<1, true>), gproj, blk, 0, stream,
                       v, wv, bv, vh, M_TOT, D_MODEL, D_MODEL, 0L, 0L, 0L, 1.0f);

    // Scores: per (b,h) [2048x64] @ [2048x64]^T / 8 -> attn (raw scores)
    const dim3 gsc(SS / 64, SS / 64, BB * N_HEADS);
    hipLaunchKernelGGL((gemm_nt<0, false>), gsc, blk, 0, stream,
                       qh, kh, (const float*)nullptr, attn,
                       SS, SS, D_K, (long)SS * D_K, (long)SS * D_K,
                       (long)SS * SS, 0.125f);

    // Softmax rows in-place
    hipLaunchKernelGGL(softmax_rows, dim3(BB * N_HEADS * SS), blk, 0, stream, attn);

    // PV: attn @ vh -> oh (merged [B,S,D])
    hipLaunchKernelGGL(gemm_nn_pv, dim3(1, SS / 64, BB * N_HEADS), blk, 0, stream,
                       attn, vh, oh);

    // Output projection: oh @ wo^T + bo -> out
    hipLaunchKernelGGL((gemm_nt<0, true>), gproj, blk, 0, stream,
                       oh, wo, bo, out, M_TOT, D_MODEL, D_MODEL, 0L, 0L, 0L, 1.0f);
}